// Round 6
// baseline (235.887 us; speedup 1.0000x reference)
//
#include <hip/hip_runtime.h>
#include <math.h>

#define N_NODES 50000
#define N_EDGES 800000
#define E_TOTAL (N_NODES + N_EDGES)
#define IN_F 256
#define OUT_F 128
#define ALPHA 0.2f

#define GEMM_WAVES ((N_NODES + 31) / 32)              // 1563 (32 rows/wave)
#define GEMM_BLOCKS ((GEMM_WAVES + 3) / 4)            // 391
#define LINK_BLOCKS ((N_EDGES + 255) / 256)           // 3125
#define NODE_BLOCKS ((N_NODES + 255) / 256)           // 196

typedef short bf16x8 __attribute__((ext_vector_type(8)));
typedef float f32x4  __attribute__((ext_vector_type(4)));

// f32 -> bf16 round-to-nearest-even (no NaN handling needed here)
static __device__ __forceinline__ unsigned short f2bf(float f) {
    unsigned int u = __float_as_uint(f);
    u += 0x7FFFu + ((u >> 16) & 1u);
    return (unsigned short)(u >> 16);
}
static __device__ __forceinline__ float bf2f(unsigned int u16) {
    return __uint_as_float(u16 << 16);
}

// ---------------- K1: fused init + Wa + WbT prep ----------------
// blocks [0,196): head/cnt init; block 196: Wa = W@a halves (+ total=0);
// blocks [197,325): WbT[n][k] = bf16(W[k][n]).
__global__ __launch_bounds__(256) void k_prep(const float* __restrict__ W,
                                              const float* __restrict__ a,
                                              int* __restrict__ head,
                                              int* __restrict__ cnt,
                                              int* __restrict__ total,
                                              float* __restrict__ Wa,
                                              unsigned short* __restrict__ WbT) {
    const int b = blockIdx.x, t = threadIdx.x;
    if (b < NODE_BLOCKS) {
        int i = b * 256 + t;
        if (i < N_NODES) { head[i] = -1; cnt[i] = 1; }  // cnt=1: implicit self-loop
    } else if (b == NODE_BLOCKS) {
        if (t == 0) *total = 0;
        const int k = t;
        const float4* wr  = (const float4*)(W + (size_t)k * OUT_F);
        const float4* av1 = (const float4*)a;
        const float4* av2 = (const float4*)(a + OUT_F);
        float s1 = 0.0f, s2 = 0.0f;
#pragma unroll 8
        for (int i = 0; i < OUT_F / 4; ++i) {
            float4 w = wr[i], x = av1[i], y = av2[i];
            s1 = fmaf(w.x, x.x, fmaf(w.y, x.y, fmaf(w.z, x.z, fmaf(w.w, x.w, s1))));
            s2 = fmaf(w.x, y.x, fmaf(w.y, y.y, fmaf(w.z, y.z, fmaf(w.w, y.w, s2))));
        }
        Wa[k] = s1;
        Wa[IN_F + k] = s2;
    } else {
        const int n = b - (NODE_BLOCKS + 1);
        WbT[(size_t)n * IN_F + t] = f2bf(W[(size_t)t * OUT_F + n]);
    }
}

// ---------------- K2: fused [MFMA GEMM + scores] and [link build] ----------
// blocks [0,391): Wh = h@W via 16x16x32 bf16 MFMA, fused f32 scores.
// blocks [391,3516): per-destination linked-list build + in-degree count
// (independent work co-scheduled; atomic latency hides under MFMA blocks).
__global__ __launch_bounds__(256) void k_gemm_link(const float* __restrict__ h,
                                                   const unsigned short* __restrict__ WbT,
                                                   const float* __restrict__ Wa,
                                                   const int* __restrict__ adj,
                                                   unsigned short* __restrict__ Whb,
                                                   float* __restrict__ s_src,
                                                   float* __restrict__ s_dst,
                                                   int* __restrict__ head,
                                                   int* __restrict__ cnt,
                                                   int2* __restrict__ list) {
    if (blockIdx.x >= GEMM_BLOCKS) {
        // ---- link part ----
        int e = (blockIdx.x - GEMM_BLOCKS) * 256 + threadIdx.x;
        if (e >= N_EDGES) return;
        int src = adj[e];
        int col = adj[N_EDGES + e];
        int old = atomicExch(&head[col], e);   // only random access: 200KB L2 array
        list[e] = make_int2(src, old);         // coalesced by edge id
        atomicAdd(&cnt[col], 1);
        return;
    }
    // ---- gemm part ----
    const int wid  = blockIdx.x * 4 + (threadIdx.x >> 6);
    const int lane = threadIdx.x & 63;
    if (wid >= GEMM_WAVES) return;
    const int m = lane & 15, grp = lane >> 4;
    const int row0 = wid * 32;

    f32x4 acc[2][8];
#pragma unroll
    for (int rt = 0; rt < 2; ++rt)
#pragma unroll
        for (int nt = 0; nt < 8; ++nt) acc[rt][nt] = (f32x4){0.f, 0.f, 0.f, 0.f};
    float sp1[2] = {0.f, 0.f}, sp2[2] = {0.f, 0.f};

    for (int kt = 0; kt < 8; ++kt) {
        const int k0 = kt * 32;
        bf16x8 hfrag[2];
#pragma unroll
        for (int rt = 0; rt < 2; ++rt) {
            int r = row0 + rt * 16 + m;
            if (r >= N_NODES) r = N_NODES - 1;   // clamp; stores guarded
            const float4* hp = (const float4*)(h + (size_t)r * IN_F + k0 + grp * 8);
            float4 x0 = hp[0], x1 = hp[1];
            const float4* wap1 = (const float4*)(Wa + k0 + grp * 8);
            const float4* wap2 = (const float4*)(Wa + IN_F + k0 + grp * 8);
            float4 a0 = wap1[0], a1 = wap1[1];
            float4 b0 = wap2[0], b1 = wap2[1];
            sp1[rt] = fmaf(x0.x, a0.x, fmaf(x0.y, a0.y, fmaf(x0.z, a0.z, fmaf(x0.w, a0.w, sp1[rt]))));
            sp1[rt] = fmaf(x1.x, a1.x, fmaf(x1.y, a1.y, fmaf(x1.z, a1.z, fmaf(x1.w, a1.w, sp1[rt]))));
            sp2[rt] = fmaf(x0.x, b0.x, fmaf(x0.y, b0.y, fmaf(x0.z, b0.z, fmaf(x0.w, b0.w, sp2[rt]))));
            sp2[rt] = fmaf(x1.x, b1.x, fmaf(x1.y, b1.y, fmaf(x1.z, b1.z, fmaf(x1.w, b1.w, sp2[rt]))));
            bf16x8 hf;
            hf[0] = (short)f2bf(x0.x); hf[1] = (short)f2bf(x0.y);
            hf[2] = (short)f2bf(x0.z); hf[3] = (short)f2bf(x0.w);
            hf[4] = (short)f2bf(x1.x); hf[5] = (short)f2bf(x1.y);
            hf[6] = (short)f2bf(x1.z); hf[7] = (short)f2bf(x1.w);
            hfrag[rt] = hf;
        }
#pragma unroll
        for (int nt = 0; nt < 8; ++nt) {
            bf16x8 wf = *(const bf16x8*)(WbT + (size_t)(nt * 16 + m) * IN_F + k0 + grp * 8);
            acc[0][nt] = __builtin_amdgcn_mfma_f32_16x16x32_bf16(wf, hfrag[0], acc[0][nt], 0, 0, 0);
            acc[1][nt] = __builtin_amdgcn_mfma_f32_16x16x32_bf16(wf, hfrag[1], acc[1][nt], 0, 0, 0);
        }
    }

#pragma unroll
    for (int rt = 0; rt < 2; ++rt) {
        const int row = row0 + rt * 16 + m;
        const bool valid = (row < N_NODES);
        float t1 = sp1[rt], t2 = sp2[rt];
        t1 += __shfl_xor(t1, 16); t1 += __shfl_xor(t1, 32);
        t2 += __shfl_xor(t2, 16); t2 += __shfl_xor(t2, 32);
        if (valid && grp == 0) { s_src[row] = t1; s_dst[row] = t2; }
        if (valid) {
            unsigned short* orow = Whb + (size_t)row * OUT_F;
#pragma unroll
            for (int nt = 0; nt < 8; ++nt) {
                f32x4 v = acc[rt][nt];
                ushort4 pk;
                pk.x = f2bf(v[0]); pk.y = f2bf(v[1]);
                pk.z = f2bf(v[2]); pk.w = f2bf(v[3]);
                *(ushort4*)(orow + nt * 16 + grp * 4) = pk;
            }
        }
    }
}

// ---------------- K3: segment offsets (order-free placement) ----------------
__global__ __launch_bounds__(256) void k_offsets(const int* __restrict__ cnt,
                                                 int* __restrict__ start,
                                                 int* __restrict__ total) {
    int i = blockIdx.x * blockDim.x + threadIdx.x;
    if (i >= N_NODES) return;
    start[i] = atomicAdd(total, cnt[i]);
}

// ---------------- K4: chain walk -> sequential pack segments + denom -------
// One THREAD per node: 50k independent chains all resident -> chase latency
// overlapped chip-wide. Single writer per pack segment (no cross-XCD line
// ping-pong). Also folds self-loop and computes softmax denominator.
__global__ __launch_bounds__(256) void k_walk(const int* __restrict__ head,
                                              const int2* __restrict__ list,
                                              const float* __restrict__ s_src,
                                              const float* __restrict__ s_dst,
                                              const int* __restrict__ start,
                                              int2* __restrict__ pack,
                                              float* __restrict__ denom) {
    int node = blockIdx.x * blockDim.x + threadIdx.x;
    if (node >= N_NODES) return;
    float sd = s_dst[node];
    int p = start[node];

    // self-loop entry
    float s0 = sd + s_src[node];
    float lr0 = (s0 > 0.0f) ? s0 : ALPHA * s0;
    float x0 = __expf(lr0);
    pack[p++] = make_int2(node, __float_as_int(x0));
    float dsum = x0;

    int e = head[node];
    while (e >= 0) {
        int2 rec = list[e];          // {src, next}
        e = rec.y;                   // advance chase ASAP
        float ss = s_src[rec.x];
        float s = sd + ss;
        float lr = (s > 0.0f) ? s : ALPHA * s;
        float x = __expf(lr);
        pack[p++] = make_int2(rec.x, __float_as_int(x));
        dsum += x;
    }
    denom[node] = dsum;
}

// ---------------- K5: gather (bf16 Wh, sequential pack), normalize, ELU ----
// One wave per node; lane owns 2 features (ushort2 as uint). Unroll x8 ->
// 8 outstanding random row loads per wave.
__global__ __launch_bounds__(256) void k_gather(const unsigned short* __restrict__ Whb,
                                                const int* __restrict__ start,
                                                const int* __restrict__ cnt,
                                                const int2* __restrict__ pack,
                                                const float* __restrict__ denom,
                                                float* __restrict__ out) {
    int node = (blockIdx.x * blockDim.x + threadIdx.x) >> 6;
    int lane = threadIdx.x & 63;
    if (node >= N_NODES) return;
    int s0 = start[node];
    int n  = cnt[node];
    const uint* __restrict__ Wv = (const uint*)Whb;   // ushort2 as uint, [N][64]

    float ax = 0.0f, ay = 0.0f;
    int j = 0;
    for (; j + 8 <= n; j += 8) {
        int2 p0 = pack[s0 + j + 0];
        int2 p1 = pack[s0 + j + 1];
        int2 p2 = pack[s0 + j + 2];
        int2 p3 = pack[s0 + j + 3];
        int2 p4 = pack[s0 + j + 4];
        int2 p5 = pack[s0 + j + 5];
        int2 p6 = pack[s0 + j + 6];
        int2 p7 = pack[s0 + j + 7];
        uint w0 = Wv[(size_t)p0.x * (OUT_F / 2) + lane];
        uint w1 = Wv[(size_t)p1.x * (OUT_F / 2) + lane];
        uint w2 = Wv[(size_t)p2.x * (OUT_F / 2) + lane];
        uint w3 = Wv[(size_t)p3.x * (OUT_F / 2) + lane];
        uint w4 = Wv[(size_t)p4.x * (OUT_F / 2) + lane];
        uint w5 = Wv[(size_t)p5.x * (OUT_F / 2) + lane];
        uint w6 = Wv[(size_t)p6.x * (OUT_F / 2) + lane];
        uint w7 = Wv[(size_t)p7.x * (OUT_F / 2) + lane];
        float x0 = __int_as_float(p0.y), x1 = __int_as_float(p1.y);
        float x2 = __int_as_float(p2.y), x3 = __int_as_float(p3.y);
        float x4 = __int_as_float(p4.y), x5 = __int_as_float(p5.y);
        float x6 = __int_as_float(p6.y), x7 = __int_as_float(p7.y);
        ax = fmaf(x0, bf2f(w0 & 0xFFFFu), ax); ay = fmaf(x0, bf2f(w0 >> 16), ay);
        ax = fmaf(x1, bf2f(w1 & 0xFFFFu), ax); ay = fmaf(x1, bf2f(w1 >> 16), ay);
        ax = fmaf(x2, bf2f(w2 & 0xFFFFu), ax); ay = fmaf(x2, bf2f(w2 >> 16), ay);
        ax = fmaf(x3, bf2f(w3 & 0xFFFFu), ax); ay = fmaf(x3, bf2f(w3 >> 16), ay);
        ax = fmaf(x4, bf2f(w4 & 0xFFFFu), ax); ay = fmaf(x4, bf2f(w4 >> 16), ay);
        ax = fmaf(x5, bf2f(w5 & 0xFFFFu), ax); ay = fmaf(x5, bf2f(w5 >> 16), ay);
        ax = fmaf(x6, bf2f(w6 & 0xFFFFu), ax); ay = fmaf(x6, bf2f(w6 >> 16), ay);
        ax = fmaf(x7, bf2f(w7 & 0xFFFFu), ax); ay = fmaf(x7, bf2f(w7 >> 16), ay);
    }
    for (; j < n; ++j) {
        int2 p = pack[s0 + j];
        uint w = Wv[(size_t)p.x * (OUT_F / 2) + lane];
        float x = __int_as_float(p.y);
        ax = fmaf(x, bf2f(w & 0xFFFFu), ax);
        ay = fmaf(x, bf2f(w >> 16), ay);
    }
    float inv = 1.0f / denom[node];
    float vx = ax * inv;
    float vy = ay * inv;
    vx = (vx > 0.0f) ? vx : expm1f(vx);
    vy = (vy > 0.0f) ? vy : expm1f(vy);
    ((float2*)(out + (size_t)node * OUT_F))[lane] = make_float2(vx, vy);
}

// ---------------- launcher ----------------
extern "C" void kernel_launch(void* const* d_in, const int* in_sizes, int n_in,
                              void* d_out, int out_size, void* d_ws, size_t ws_size,
                              hipStream_t stream) {
    const float* h   = (const float*)d_in[0];
    const int*   adj = (const int*)d_in[1];
    const float* W   = (const float*)d_in[2];
    const float* a   = (const float*)d_in[3];
    float* out = (float*)d_out;

    // workspace layout (256B-aligned chunks)
    char* ws = (char*)d_ws;
    const size_t SZ_WHB = (size_t)N_NODES * OUT_F * 2;   // 12,800,000 (mult of 256)
    const size_t SZ_N   = 200704;                        // >= N_NODES*4, 256-aligned
    const size_t SZ_E8  = (size_t)N_EDGES * 8;           // 6,400,000 (mult of 256)
    unsigned short* Whb = (unsigned short*)(ws);
    float* s_src   = (float*)(ws + SZ_WHB);
    float* s_dst   = (float*)(ws + SZ_WHB + SZ_N);
    int*   head    = (int*)  (ws + SZ_WHB + 2 * SZ_N);
    int*   cnt     = (int*)  (ws + SZ_WHB + 3 * SZ_N);
    int*   start   = (int*)  (ws + SZ_WHB + 4 * SZ_N);
    float* denom   = (float*)(ws + SZ_WHB + 5 * SZ_N);
    int*   total   = (int*)  (ws + SZ_WHB + 6 * SZ_N);
    float* Wa      = (float*)(ws + SZ_WHB + 6 * SZ_N + 256);            // 2KB
    unsigned short* WbT = (unsigned short*)(ws + SZ_WHB + 6 * SZ_N + 256 + 2048); // 64KB
    int2*  list    = (int2*) (ws + SZ_WHB + 6 * SZ_N + 256 + 2048 + 65536);
    int2*  pack    = (int2*) (ws + SZ_WHB + 6 * SZ_N + 256 + 2048 + 65536 + SZ_E8);

    (void)in_sizes; (void)n_in; (void)out_size; (void)ws_size;

    k_prep     <<<NODE_BLOCKS + 1 + OUT_F, 256, 0, stream>>>(W, a, head, cnt, total, Wa, WbT);
    k_gemm_link<<<GEMM_BLOCKS + LINK_BLOCKS, 256, 0, stream>>>(h, WbT, Wa, adj, Whb,
                                                               s_src, s_dst, head, cnt, list);
    k_offsets  <<<NODE_BLOCKS, 256, 0, stream>>>(cnt, start, total);
    k_walk     <<<NODE_BLOCKS, 256, 0, stream>>>(head, list, s_src, s_dst, start, pack, denom);
    k_gather   <<<(N_NODES * 64 + 255) / 256, 256, 0, stream>>>(Whb, start, cnt, pack, denom, out);
}